// Round 1
// baseline (483.815 us; speedup 1.0000x reference)
//
#include <hip/hip_runtime.h>
#include <math.h>

typedef __bf16 bf16x8 __attribute__((ext_vector_type(8)));
typedef float f32x4 __attribute__((ext_vector_type(4)));

#define DDIM 1024
#define HDIM 4096
#define NE 8
#define TT 4096           // tokens = 2*2048
#define CAP 9216          // 8192 pairs + 8*128 padding capacity

// ---------------- ws layout (bytes) ----------------
// ctrl ints: [0..7]=counts, [8..16]=padded offsets, [20..27]=cursors
static const size_t OFF_CTRL   = 0;                                   // 256 B
static const size_t OFF_ROWMAP = 256;                                 // CAP*4
static const size_t OFF_ROWPOS = OFF_ROWMAP + (size_t)CAP * 4;        // TT*2*4
static const size_t OFF_TOKE   = OFF_ROWPOS + (size_t)TT * 2 * 4;
static const size_t OFF_TOKW   = OFF_TOKE + (size_t)TT * 2 * 4;
static const size_t OFF_XB     = OFF_TOKW + (size_t)TT * 2 * 4;       // TT*D bf16
static const size_t OFF_W1T    = OFF_XB + (size_t)TT * DDIM * 2;      // E*H*D bf16 (N-major)
static const size_t OFF_W2T    = OFF_W1T + (size_t)NE * HDIM * DDIM * 2; // E*D*H bf16 (N-major)
static const size_t OFF_H      = OFF_W2T + (size_t)NE * DDIM * HDIM * 2; // CAP*H bf16
static const size_t OFF_PO     = OFF_H + (size_t)CAP * HDIM * 2;         // CAP*D f32
static const size_t WS_NEED    = OFF_PO + (size_t)CAP * DDIM * 4;     // ~244 MiB

__device__ __forceinline__ unsigned short f2bf(float f) {
  unsigned int u = __builtin_bit_cast(unsigned int, f);
  u = (u + 0x7FFFu + ((u >> 16) & 1u)) >> 16;
  return (unsigned short)u;
}

__device__ __forceinline__ void async16(void* lds, const void* g) {
  __builtin_amdgcn_global_load_lds(
      (__attribute__((address_space(1))) void*)g,
      (__attribute__((address_space(3))) void*)lds, 16, 0, 0);
}

__device__ __forceinline__ float gelu_exact(float v) {
  return 0.5f * v * (1.0f + erff(v * 0.70710678118654752f));
}

// ---------------- router: logits(fp32), top-2, weights; x -> bf16 ----------------
__global__ __launch_bounds__(256) void router_k(
    const float* __restrict__ x, const float* __restrict__ Wr, const float* __restrict__ br,
    unsigned short* __restrict__ xb, int* __restrict__ ctrl,
    int* __restrict__ toke, float* __restrict__ tokw) {
  int tid = threadIdx.x, lane = tid & 63, wid = tid >> 6;
  int t = blockIdx.x * 4 + wid;
  const float* xr = x + (size_t)t * DDIM;
  float acc[NE];
#pragma unroll
  for (int e = 0; e < NE; ++e) acc[e] = 0.f;
#pragma unroll
  for (int it = 0; it < DDIM / 64; ++it) {
    int d = lane + it * 64;
    float xv = xr[d];
    xb[(size_t)t * DDIM + d] = f2bf(xv);
    const float4* w4 = (const float4*)(Wr + (size_t)d * NE);
    float4 wa = w4[0], wb = w4[1];
    acc[0] += xv * wa.x; acc[1] += xv * wa.y; acc[2] += xv * wa.z; acc[3] += xv * wa.w;
    acc[4] += xv * wb.x; acc[5] += xv * wb.y; acc[6] += xv * wb.z; acc[7] += xv * wb.w;
  }
#pragma unroll
  for (int e = 0; e < NE; ++e) {
#pragma unroll
    for (int s = 32; s > 0; s >>= 1) acc[e] += __shfl_xor(acc[e], s, 64);
  }
  if (lane == 0) {
    float l[NE];
#pragma unroll
    for (int e = 0; e < NE; ++e) l[e] = acc[e] + br[e];
    int i0 = 0; float m0 = l[0];
#pragma unroll
    for (int e = 1; e < NE; ++e) if (l[e] > m0) { m0 = l[e]; i0 = e; }
    int i1 = -1; float m1 = -3.4e38f;
#pragma unroll
    for (int e = 0; e < NE; ++e) if (e != i0 && l[e] > m1) { m1 = l[e]; i1 = e; }
    float e1 = expf(m1 - m0);
    float s = 1.f + e1;
    toke[2 * t] = i0;  toke[2 * t + 1] = i1;
    tokw[2 * t] = 1.f / s;  tokw[2 * t + 1] = e1 / s;
    atomicAdd(&ctrl[i0], 1);
    atomicAdd(&ctrl[i1], 1);
  }
}

// ---------------- prefix scan of padded counts ----------------
__global__ void scan_k(int* ctrl) {
  if (threadIdx.x == 0) {
    int off = 0;
    for (int e = 0; e < NE; ++e) {
      ctrl[8 + e] = off;
      ctrl[20 + e] = off;
      off += ((ctrl[e] + 127) >> 7) << 7;
    }
    ctrl[16] = off;
  }
}

// ---------------- assign rows ----------------
__global__ __launch_bounds__(256) void assign_k(
    const int* __restrict__ toke, int* ctrl,
    int* __restrict__ rowmap, int* __restrict__ rowpos) {
  int t = blockIdx.x * 256 + threadIdx.x;
#pragma unroll
  for (int k = 0; k < 2; ++k) {
    int e = toke[2 * t + k];
    int r = atomicAdd(&ctrl[20 + e], 1);
    rowmap[r] = t;
    rowpos[2 * t + k] = r;
  }
}

// ---------------- fp32 -> bf16 transpose convert: src[e][K_][N_] -> dst[e][N_][K_] ----------------
__global__ __launch_bounds__(256) void convT_k(
    const float* __restrict__ src, unsigned short* __restrict__ dst, int K_, int N_) {
  __shared__ unsigned short tile[64][65];
  int e = blockIdx.z;
  int kb = blockIdx.y << 6, nb = blockIdx.x << 6;
  int tid = threadIdx.x, cl = tid & 63, rw = tid >> 6;
  const float* s = src + (size_t)e * K_ * N_;
#pragma unroll
  for (int i = 0; i < 16; ++i) {
    int k = rw + i * 4;
    tile[k][cl] = f2bf(s[(size_t)(kb + k) * N_ + nb + cl]);
  }
  __syncthreads();
  unsigned short* dp = dst + (size_t)e * N_ * K_;
#pragma unroll
  for (int i = 0; i < 16; ++i) {
    int n = rw + i * 4;
    dp[(size_t)(nb + n) * K_ + kb + cl] = tile[cl][n];
  }
}

// ---------------- grouped expert GEMM: Out[r][n] = act(sum_k A[r][k] * Bt[e][n][k] + bias[e][n]) ----------------
template <int KTOT, int NTOT, bool GATHER, bool DOGELU>
__global__ __launch_bounds__(256, 2) void gemm_k(
    const unsigned short* __restrict__ A, const unsigned short* __restrict__ Bt,
    const int* __restrict__ ctrl, const int* __restrict__ rowmap,
    const float* __restrict__ bias,
    unsigned short* __restrict__ outb, float* __restrict__ outf) {
  __shared__ unsigned short Asm[128 * 64];
  __shared__ unsigned short Bsm[128 * 64];
  int e = blockIdx.z, ry = blockIdx.y, cx = blockIdx.x;
  int off0 = ctrl[8 + e], off1 = ctrl[8 + e + 1];
  int row0 = off0 + (ry << 7);
  if (row0 >= off1) return;
  int col0 = cx << 7;
  int tid = threadIdx.x, lane = tid & 63, wid = tid >> 6;

  const unsigned short* Asrc[4];
  const unsigned short* Bsrc[4];
#pragma unroll
  for (int c = 0; c < 4; ++c) {
    int ar = row0 + (c << 5) + (tid >> 3);
    size_t arow = GATHER ? (size_t)rowmap[ar] : (size_t)ar;
    Asrc[c] = A + arow * KTOT + ((tid & 7) << 3);
    int brw = col0 + (c << 5) + (tid >> 3);
    Bsrc[c] = Bt + ((size_t)e * NTOT + brw) * KTOT + ((tid & 7) << 3);
  }

  f32x4 acc[4][4];
#pragma unroll
  for (int m = 0; m < 4; ++m)
#pragma unroll
    for (int n = 0; n < 4; ++n) acc[m][n] = (f32x4){0.f, 0.f, 0.f, 0.f};

  int wr = wid >> 1, wc = wid & 1;
  int arow_rd = ((wr << 6) + (lane & 15)) << 6;  // element index into Asm
  int brow_rd = ((wc << 6) + (lane & 15)) << 6;
  int koff = (lane >> 4) << 3;
  char* AsmB = (char*)Asm;
  char* BsmB = (char*)Bsm;

  for (int k0 = 0; k0 < KTOT; k0 += 64) {
#pragma unroll
    for (int c = 0; c < 4; ++c) {
      async16(AsmB + ((c << 8) + (wid << 6)) * 16, Asrc[c] + k0);
      async16(BsmB + ((c << 8) + (wid << 6)) * 16, Bsrc[c] + k0);
    }
    __syncthreads();
#pragma unroll
    for (int kk = 0; kk < 64; kk += 32) {
      bf16x8 af[4], bfr[4];
#pragma unroll
      for (int m = 0; m < 4; ++m)
        af[m] = *(const bf16x8*)&Asm[arow_rd + (m << 10) + kk + koff];
#pragma unroll
      for (int n = 0; n < 4; ++n)
        bfr[n] = *(const bf16x8*)&Bsm[brow_rd + (n << 10) + kk + koff];
#pragma unroll
      for (int m = 0; m < 4; ++m)
#pragma unroll
        for (int n = 0; n < 4; ++n)
          acc[m][n] = __builtin_amdgcn_mfma_f32_16x16x32_bf16(af[m], bfr[n], acc[m][n], 0, 0, 0);
    }
    __syncthreads();
  }

  int r_b = (lane >> 4) << 2;
  int c_b = lane & 15;
#pragma unroll
  for (int m = 0; m < 4; ++m) {
#pragma unroll
    for (int n = 0; n < 4; ++n) {
      int col = col0 + (wc << 6) + (n << 4) + c_b;
      float bv = bias[e * NTOT + col];
#pragma unroll
      for (int r = 0; r < 4; ++r) {
        int row = row0 + (wr << 6) + (m << 4) + r_b + r;
        float v = acc[m][n][r] + bv;
        if (DOGELU) {
          v = gelu_exact(v);
          outb[(size_t)row * NTOT + col] = f2bf(v);
        } else {
          outf[(size_t)row * NTOT + col] = v;
        }
      }
    }
  }
}

// ---------------- gather: out[t] = w0*pair0 + w1*pair1 ----------------
__global__ __launch_bounds__(256) void gather_k(
    const float* __restrict__ pout, const int* __restrict__ rowpos,
    const float* __restrict__ tokw, float* __restrict__ out) {
  int t = blockIdx.x, d = threadIdx.x << 2;
  int r0 = rowpos[2 * t], r1 = rowpos[2 * t + 1];
  float w0 = tokw[2 * t], w1 = tokw[2 * t + 1];
  float4 a = *(const float4*)&pout[(size_t)r0 * DDIM + d];
  float4 b = *(const float4*)&pout[(size_t)r1 * DDIM + d];
  float4 o;
  o.x = w0 * a.x + w1 * b.x;
  o.y = w0 * a.y + w1 * b.y;
  o.z = w0 * a.z + w1 * b.z;
  o.w = w0 * a.w + w1 * b.w;
  *(float4*)&out[(size_t)t * DDIM + d] = o;
}

extern "C" void kernel_launch(void* const* d_in, const int* in_sizes, int n_in,
                              void* d_out, int out_size, void* d_ws, size_t ws_size,
                              hipStream_t stream) {
  const float* x  = (const float*)d_in[0];
  const float* W1 = (const float*)d_in[1];
  const float* b1 = (const float*)d_in[2];
  const float* W2 = (const float*)d_in[3];
  const float* b2 = (const float*)d_in[4];
  const float* Wr = (const float*)d_in[5];
  const float* br = (const float*)d_in[6];
  float* out = (float*)d_out;

  if (ws_size < WS_NEED) return;  // workspace too small — re-plan if this trips

  char* ws = (char*)d_ws;
  int* ctrl            = (int*)(ws + OFF_CTRL);
  int* rowmap          = (int*)(ws + OFF_ROWMAP);
  int* rowpos          = (int*)(ws + OFF_ROWPOS);
  int* toke            = (int*)(ws + OFF_TOKE);
  float* tokw          = (float*)(ws + OFF_TOKW);
  unsigned short* xb   = (unsigned short*)(ws + OFF_XB);
  unsigned short* W1T  = (unsigned short*)(ws + OFF_W1T);
  unsigned short* W2T  = (unsigned short*)(ws + OFF_W2T);
  unsigned short* hbuf = (unsigned short*)(ws + OFF_H);
  float* pout          = (float*)(ws + OFF_PO);

  // zero ctrl + rowmap (padded rows read rowmap -> must be a valid token index)
  hipMemsetAsync(ws, 0, OFF_ROWPOS, stream);

  router_k<<<TT / 4, 256, 0, stream>>>(x, Wr, br, xb, ctrl, toke, tokw);
  scan_k<<<1, 64, 0, stream>>>(ctrl);
  assign_k<<<TT / 256, 256, 0, stream>>>(toke, ctrl, rowmap, rowpos);

  // W1: [E][1024][4096] -> W1T [E][4096][1024]
  convT_k<<<dim3(HDIM / 64, DDIM / 64, NE), 256, 0, stream>>>(W1, W1T, DDIM, HDIM);
  // W2: [E][4096][1024] -> W2T [E][1024][4096]
  convT_k<<<dim3(DDIM / 64, HDIM / 64, NE), 256, 0, stream>>>(W2, W2T, HDIM, DDIM);

  // GEMM1: h = gelu(x_rows @ W1[e] + b1[e])   M=rows, N=4096, K=1024
  gemm_k<DDIM, HDIM, true, true><<<dim3(HDIM / 128, 32, NE), 256, 0, stream>>>(
      xb, W1T, ctrl, rowmap, b1, hbuf, nullptr);
  // GEMM2: pout = h @ W2[e] + b2[e]           M=rows, N=1024, K=4096
  gemm_k<HDIM, DDIM, false, false><<<dim3(DDIM / 128, 32, NE), 256, 0, stream>>>(
      hbuf, W2T, ctrl, rowmap, b2, nullptr, pout);

  gather_k<<<TT, 256, 0, stream>>>(pout, rowpos, tokw, out);
}